// Round 2
// baseline (476.662 us; speedup 1.0000x reference)
//
#include <hip/hip_runtime.h>

#define B_SZ   1024
#define OUT_SZ 512
#define IN_SZ  1024

#define BT 128            // b-tile per block
#define OT 64             // o-tile per block
#define KT 16             // k-step staged in LDS
#define KSPLIT 16
#define KC (IN_SZ / KSPLIT)   // 64 k per block

__global__ __launch_bounds__(256) void rbf_zero(float4* p, int n4) {
    int i = blockIdx.x * blockDim.x + threadIdx.x;
    if (i < n4) p[i] = make_float4(0.f, 0.f, 0.f, 0.f);
}

// partial z[b,o] over this block's K-slice.
// use_ws=1: plain stores to partial[kz][b][o]; use_ws=0: atomicAdd into zbuf.
__global__ __launch_bounds__(256, 4) void rbf_main(
    const float* __restrict__ x, const float* __restrict__ w,
    const float* __restrict__ u, float* __restrict__ partial, int use_ws)
{
    // +4 pad: keeps float4 alignment (row strides 132/68 are 16B multiples)
    // and rotates banks by 4 per k-row.
    __shared__ __align__(16) float xs[KT][BT + 4];
    __shared__ __align__(16) float us[KT][OT + 4];
    __shared__ __align__(16) float qs[KT][OT + 4];  // q = u*w

    const int t     = threadIdx.x;
    const int kk_s  = t & 15;     // staging: k index
    const int row_s = t >> 4;     // staging: row group 0..15

    const int bBase = blockIdx.x * BT;
    const int oBase = blockIdx.y * OT;
    const int kz    = blockIdx.z;
    const int kBase = kz * KC;

    const int to = t & 15;        // compute: o-group (o frag = to*4 .. +4)
    const int tb = t >> 4;        // compute: b-group (b frag = tb*8 .. +8)

    float acc[8][4];
    #pragma unroll
    for (int i = 0; i < 8; ++i)
        #pragma unroll
        for (int j = 0; j < 4; ++j) acc[i][j] = 0.f;

    for (int kc = 0; kc < KC; kc += KT) {
        const int k0 = kBase + kc;

        // stage x: KT x BT (2048 elems, 8 per thread)
        #pragma unroll
        for (int j = 0; j < 8; ++j) {
            int b_l = row_s + j * 16;
            xs[kk_s][b_l] = x[(size_t)(bBase + b_l) * IN_SZ + (k0 + kk_s)];
        }
        // stage u and q=u*w: KT x OT (1024 elems each, 4 per thread)
        #pragma unroll
        for (int j = 0; j < 4; ++j) {
            int o_l = row_s + j * 16;
            size_t gi = (size_t)(oBase + o_l) * IN_SZ + (k0 + kk_s);
            float uv = u[gi];
            float wv = w[gi];
            us[kk_s][o_l] = uv;
            qs[kk_s][o_l] = uv * wv;
        }
        __syncthreads();

        #pragma unroll
        for (int kk = 0; kk < KT; ++kk) {
            float4 xa = *(const float4*)&xs[kk][tb * 8];
            float4 xb = *(const float4*)&xs[kk][tb * 8 + 4];
            float4 uu = *(const float4*)&us[kk][to * 4];
            float4 qq = *(const float4*)&qs[kk][to * 4];
            float xv[8] = {xa.x, xa.y, xa.z, xa.w, xb.x, xb.y, xb.z, xb.w};
            float uv[4] = {uu.x, uu.y, uu.z, uu.w};
            float qv[4] = {qq.x, qq.y, qq.z, qq.w};
            #pragma unroll
            for (int i = 0; i < 8; ++i)
                #pragma unroll
                for (int j = 0; j < 4; ++j) {
                    float d = fmaf(uv[j], xv[i], -qv[j]);   // u*x - u*w
                    acc[i][j] = fmaf(d, d, acc[i][j]);
                }
        }
        __syncthreads();
    }

    if (use_ws) {
        // coalesced float4 stores: lane group (to=0..15) covers o contiguously
        #pragma unroll
        for (int i = 0; i < 8; ++i) {
            int b = bBase + tb * 8 + i;
            size_t pidx = ((size_t)kz * B_SZ + b) * OUT_SZ + (oBase + to * 4);
            float4 v = make_float4(acc[i][0], acc[i][1], acc[i][2], acc[i][3]);
            *(float4*)&partial[pidx] = v;
        }
    } else {
        #pragma unroll
        for (int i = 0; i < 8; ++i) {
            int b = bBase + tb * 8 + i;
            #pragma unroll
            for (int j = 0; j < 4; ++j) {
                int o = oBase + to * 4 + j;
                atomicAdd(&partial[(size_t)b * OUT_SZ + o], acc[i][j]);
            }
        }
    }
}

// sum KSPLIT partials, then out = a + exp(-z)*(1-2a)
__global__ __launch_bounds__(256) void rbf_reduce(
    const float* __restrict__ partial, const float* __restrict__ andor,
    float* __restrict__ out)
{
    int idx = blockIdx.x * blockDim.x + threadIdx.x;
    if (idx < B_SZ * OUT_SZ) {
        float z = 0.f;
        #pragma unroll
        for (int kz = 0; kz < KSPLIT; ++kz)
            z += partial[(size_t)kz * (B_SZ * OUT_SZ) + idx];
        float a = andor[idx & (OUT_SZ - 1)];
        float y = __expf(-z);
        out[idx] = fmaf(y, 1.f - 2.f * a, a);
    }
}

// in-place epilogue for the atomic fallback path
__global__ __launch_bounds__(256) void rbf_epilogue(
    float* __restrict__ zio, const float* __restrict__ andor)
{
    int idx = blockIdx.x * blockDim.x + threadIdx.x;
    if (idx < B_SZ * OUT_SZ) {
        float a = andor[idx & (OUT_SZ - 1)];
        float zv = zio[idx];
        float y = __expf(-zv);
        zio[idx] = fmaf(y, 1.f - 2.f * a, a);
    }
}

extern "C" void kernel_launch(void* const* d_in, const int* in_sizes, int n_in,
                              void* d_out, int out_size, void* d_ws, size_t ws_size,
                              hipStream_t stream) {
    const float* x = (const float*)d_in[0];   // [B, IN]
    const float* w = (const float*)d_in[1];   // [OUT, IN]
    const float* u = (const float*)d_in[2];   // [OUT, IN]
    const float* a = (const float*)d_in[3];   // [1, OUT]
    float* out = (float*)d_out;               // [B, OUT]

    const int n = B_SZ * OUT_SZ;
    const size_t ws_needed = (size_t)KSPLIT * B_SZ * OUT_SZ * sizeof(float);
    dim3 grid(B_SZ / BT, OUT_SZ / OT, KSPLIT);   // 8 x 8 x 16 = 1024 blocks

    if (ws_size >= ws_needed) {
        float* part = (float*)d_ws;
        rbf_main<<<grid, dim3(256), 0, stream>>>(x, w, u, part, 1);
        rbf_reduce<<<dim3((n + 255) / 256), dim3(256), 0, stream>>>(part, a, out);
    } else {
        // fallback: atomic accumulation directly into d_out
        rbf_zero<<<dim3((n / 4 + 255) / 256), dim3(256), 0, stream>>>((float4*)out, n / 4);
        rbf_main<<<grid, dim3(256), 0, stream>>>(x, w, u, out, 0);
        rbf_epilogue<<<dim3((n + 255) / 256), dim3(256), 0, stream>>>(out, a);
    }
}

// Round 3
// 105.299 us; speedup vs baseline: 4.5267x; 4.5267x over previous
//
#include <hip/hip_runtime.h>

#define B_SZ   1024
#define OUT_SZ 512
#define IN_SZ  1024

#define BT 128            // b-tile per block
#define OT 128            // o-tile per block
#define KT 16             // k-step staged in LDS
#define KSPLIT 16
#define KC (IN_SZ / KSPLIT)   // 64 k per block
#define NKT (KC / KT)         // 4 double-buffered stages

__global__ __launch_bounds__(256) void rbf_zero(float4* p, int n4) {
    int i = blockIdx.x * blockDim.x + threadIdx.x;
    if (i < n4) p[i] = make_float4(0.f, 0.f, 0.f, 0.f);
}

// partial z[b,o] over this block's K-slice. 8x8 per-thread fragment,
// double-buffered LDS with register prefetch, one barrier per K-tile.
// NOTE: no min-waves launch bound — R2 showed (256,4) forces VGPR=64 and
// spills 1.4 GB to scratch. Let the allocator keep the 64-reg accumulator.
__global__ __launch_bounds__(256) void rbf_main(
    const float* __restrict__ x, const float* __restrict__ w,
    const float* __restrict__ u, float* __restrict__ partial, int use_ws)
{
    // +4 pad keeps rows 16B-aligned (132 floats = 528 B) for float4 reads.
    __shared__ __align__(16) float xs[2][KT][BT + 4];
    __shared__ __align__(16) float us[2][KT][OT + 4];
    __shared__ __align__(16) float qs[2][KT][OT + 4];  // q = u*w

    const int t     = threadIdx.x;
    const int bBase = blockIdx.x * BT;
    const int oBase = blockIdx.y * OT;
    const int kz    = blockIdx.z;
    const int kBase = kz * KC;

    const int to = t & 15;        // o-frag = to*8 .. +8
    const int tb = t >> 4;        // b-frag = tb*8 .. +8

    float acc[8][8];
    #pragma unroll
    for (int i = 0; i < 8; ++i)
        #pragma unroll
        for (int j = 0; j < 8; ++j) acc[i][j] = 0.f;

    float4 xr[2], ur[2], wr[2];   // register prefetch buffers

    // float4-granular staging: idx = j*256+t covers 512 float4 slots;
    // row = idx>>2 (0..127 = b_l or o_l), kq = idx&3 (16B chunk along k).
    auto load_tile = [&](int k0) {
        #pragma unroll
        for (int j = 0; j < 2; ++j) {
            int idx = j * 256 + t;
            int row = idx >> 2;
            int kq  = idx & 3;
            xr[j] = *(const float4*)&x[(size_t)(bBase + row) * IN_SZ + k0 + kq * 4];
            ur[j] = *(const float4*)&u[(size_t)(oBase + row) * IN_SZ + k0 + kq * 4];
            wr[j] = *(const float4*)&w[(size_t)(oBase + row) * IN_SZ + k0 + kq * 4];
        }
    };
    auto store_tile = [&](int buf) {
        #pragma unroll
        for (int j = 0; j < 2; ++j) {
            int idx = j * 256 + t;
            int row = idx >> 2;
            int kq  = idx & 3;
            float xv[4] = {xr[j].x, xr[j].y, xr[j].z, xr[j].w};
            float uv[4] = {ur[j].x, ur[j].y, ur[j].z, ur[j].w};
            float wv[4] = {wr[j].x, wr[j].y, wr[j].z, wr[j].w};
            #pragma unroll
            for (int c = 0; c < 4; ++c) {
                xs[buf][kq * 4 + c][row] = xv[c];
                us[buf][kq * 4 + c][row] = uv[c];
                qs[buf][kq * 4 + c][row] = uv[c] * wv[c];
            }
        }
    };

    load_tile(kBase);
    store_tile(0);
    __syncthreads();

    for (int kt = 0; kt < NKT; ++kt) {
        const int cur = kt & 1;
        if (kt + 1 < NKT) load_tile(kBase + (kt + 1) * KT);  // hide global latency behind compute

        #pragma unroll 4
        for (int kk = 0; kk < KT; ++kk) {
            const float4 xa = *(const float4*)&xs[cur][kk][tb * 8];
            const float4 xb = *(const float4*)&xs[cur][kk][tb * 8 + 4];
            const float4 ua = *(const float4*)&us[cur][kk][to * 8];
            const float4 ub = *(const float4*)&us[cur][kk][to * 8 + 4];
            const float4 qa = *(const float4*)&qs[cur][kk][to * 8];
            const float4 qb = *(const float4*)&qs[cur][kk][to * 8 + 4];
            float xv[8] = {xa.x, xa.y, xa.z, xa.w, xb.x, xb.y, xb.z, xb.w};
            float uv[8] = {ua.x, ua.y, ua.z, ua.w, ub.x, ub.y, ub.z, ub.w};
            float qv[8] = {qa.x, qa.y, qa.z, qa.w, qb.x, qb.y, qb.z, qb.w};
            #pragma unroll
            for (int i = 0; i < 8; ++i)
                #pragma unroll
                for (int j = 0; j < 8; ++j) {
                    float d = fmaf(uv[j], xv[i], -qv[j]);   // u*x - u*w
                    acc[i][j] = fmaf(d, d, acc[i][j]);
                }
        }

        if (kt + 1 < NKT) store_tile(cur ^ 1);  // other buffer: no pre-barrier needed
        __syncthreads();
    }

    if (use_ws) {
        #pragma unroll
        for (int i = 0; i < 8; ++i) {
            int b = bBase + tb * 8 + i;
            size_t base = ((size_t)kz * B_SZ + b) * OUT_SZ + oBase + to * 8;
            *(float4*)&partial[base]     = make_float4(acc[i][0], acc[i][1], acc[i][2], acc[i][3]);
            *(float4*)&partial[base + 4] = make_float4(acc[i][4], acc[i][5], acc[i][6], acc[i][7]);
        }
    } else {
        #pragma unroll
        for (int i = 0; i < 8; ++i) {
            int b = bBase + tb * 8 + i;
            #pragma unroll
            for (int j = 0; j < 8; ++j)
                atomicAdd(&partial[(size_t)b * OUT_SZ + (oBase + to * 8 + j)], acc[i][j]);
        }
    }
}

// sum KSPLIT partials, then out = a + exp(-z)*(1-2a)
__global__ __launch_bounds__(256) void rbf_reduce(
    const float* __restrict__ partial, const float* __restrict__ andor,
    float* __restrict__ out)
{
    int idx = blockIdx.x * blockDim.x + threadIdx.x;
    if (idx < B_SZ * OUT_SZ) {
        float z = 0.f;
        #pragma unroll
        for (int kz = 0; kz < KSPLIT; ++kz)
            z += partial[(size_t)kz * (B_SZ * OUT_SZ) + idx];
        float a = andor[idx & (OUT_SZ - 1)];
        float y = __expf(-z);
        out[idx] = fmaf(y, 1.f - 2.f * a, a);
    }
}

// in-place epilogue for the atomic fallback path
__global__ __launch_bounds__(256) void rbf_epilogue(
    float* __restrict__ zio, const float* __restrict__ andor)
{
    int idx = blockIdx.x * blockDim.x + threadIdx.x;
    if (idx < B_SZ * OUT_SZ) {
        float a = andor[idx & (OUT_SZ - 1)];
        float zv = zio[idx];
        float y = __expf(-zv);
        zio[idx] = fmaf(y, 1.f - 2.f * a, a);
    }
}

extern "C" void kernel_launch(void* const* d_in, const int* in_sizes, int n_in,
                              void* d_out, int out_size, void* d_ws, size_t ws_size,
                              hipStream_t stream) {
    const float* x = (const float*)d_in[0];   // [B, IN]
    const float* w = (const float*)d_in[1];   // [OUT, IN]
    const float* u = (const float*)d_in[2];   // [OUT, IN]
    const float* a = (const float*)d_in[3];   // [1, OUT]
    float* out = (float*)d_out;               // [B, OUT]

    const int n = B_SZ * OUT_SZ;
    const size_t ws_needed = (size_t)KSPLIT * B_SZ * OUT_SZ * sizeof(float);
    dim3 grid(B_SZ / BT, OUT_SZ / OT, KSPLIT);   // 8 x 4 x 16 = 512 blocks

    if (ws_size >= ws_needed) {
        float* part = (float*)d_ws;
        rbf_main<<<grid, dim3(256), 0, stream>>>(x, w, u, part, 1);
        rbf_reduce<<<dim3((n + 255) / 256), dim3(256), 0, stream>>>(part, a, out);
    } else {
        // fallback: atomic accumulation directly into d_out
        rbf_zero<<<dim3((n / 4 + 255) / 256), dim3(256), 0, stream>>>((float4*)out, n / 4);
        rbf_main<<<grid, dim3(256), 0, stream>>>(x, w, u, out, 0);
        rbf_epilogue<<<dim3((n + 255) / 256), dim3(256), 0, stream>>>(out, a);
    }
}

// Round 4
// 87.006 us; speedup vs baseline: 5.4785x; 1.2103x over previous
//
#include <hip/hip_runtime.h>

#define B_SZ   1024
#define OUT_SZ 512
#define IN_SZ  1024
#define K2     2048              // [x^2 | x] concatenated K
#define NKSTEP 65                // 64 real k-steps of 32 + 1 bias step
#define MT     64                // M tiles of 16
#define NT     32                // N tiles of 16

typedef __bf16 bf16x8 __attribute__((ext_vector_type(8)));
typedef float  f32x4  __attribute__((ext_vector_type(4)));

// ---- workspace layout (all 16B aligned) ----
// A_shuf: [MT][NKSTEP][64 lanes][8]  bf16   = 4,259,840 B
// B_shuf: [NT][NKSTEP][64 lanes][8]  bf16   = 2,129,920 B
// part  : [2][B_SZ][OUT_SZ]          f32    = 4,194,304 B
#define A_ELEMS ((size_t)MT * NKSTEP * 64 * 8)
#define B_ELEMS ((size_t)NT * NKSTEP * 64 * 8)
#define OFF_B   (A_ELEMS * 2)
#define OFF_P   (A_ELEMS * 2 + B_ELEMS * 2)

// A_shuf[mTile][kStep][lane][j] = A[b = mTile*16 + (lane&15)][k = kStep*32 + (lane>>4)*8 + j]
// where A[b][k] = x[b][k]^2 (k<1024) | x[b][k-1024] (k<2048) | (k-step 64: 1 at j==0,quad==0)
__global__ __launch_bounds__(256) void rbf_prep_a(
    const float* __restrict__ x, __bf16* __restrict__ Ash)
{
    int t = blockIdx.x * 256 + threadIdx.x;          // 64*65*64 = 266240 threads
    int lane  = t & 63;
    int tmp   = t >> 6;
    int kStep = tmp % NKSTEP;
    int mTile = tmp / NKSTEP;
    int b     = mTile * 16 + (lane & 15);
    int quad  = lane >> 4;

    bf16x8 v;
    if (kStep < 64) {
        int kk = kStep * 32 + quad * 8;              // multiple of 8, region-pure
        if (kk < IN_SZ) {
            const float4 f0 = *(const float4*)&x[(size_t)b * IN_SZ + kk];
            const float4 f1 = *(const float4*)&x[(size_t)b * IN_SZ + kk + 4];
            float f[8] = {f0.x, f0.y, f0.z, f0.w, f1.x, f1.y, f1.z, f1.w};
            #pragma unroll
            for (int j = 0; j < 8; ++j) v[j] = (__bf16)(f[j] * f[j]);
        } else {
            int i0 = kk - IN_SZ;
            const float4 f0 = *(const float4*)&x[(size_t)b * IN_SZ + i0];
            const float4 f1 = *(const float4*)&x[(size_t)b * IN_SZ + i0 + 4];
            float f[8] = {f0.x, f0.y, f0.z, f0.w, f1.x, f1.y, f1.z, f1.w};
            #pragma unroll
            for (int j = 0; j < 8; ++j) v[j] = (__bf16)f[j];
        }
    } else {                                         // bias step: A ext col = 1
        #pragma unroll
        for (int j = 0; j < 8; ++j) v[j] = (__bf16)0.f;
        if (quad == 0) v[0] = (__bf16)1.f;
    }
    *(bf16x8*)&Ash[(size_t)t * 8] = v;               // fully coalesced 16B stores
}

// B_shuf[nTile][kStep][lane][j] = Bm[o = nTile*16 + (lane&15)][k]
// Bm[o][k] = u^2 (k<1024) | -2*u^2*w (k<2048) | 0 (bias step, r filled by rbf_prep_r)
__global__ __launch_bounds__(256) void rbf_prep_b(
    const float* __restrict__ w, const float* __restrict__ u,
    __bf16* __restrict__ Bsh)
{
    int t = blockIdx.x * 256 + threadIdx.x;          // 32*65*64 = 133120 threads
    int lane  = t & 63;
    int tmp   = t >> 6;
    int kStep = tmp % NKSTEP;
    int nTile = tmp / NKSTEP;
    int o     = nTile * 16 + (lane & 15);
    int quad  = lane >> 4;

    bf16x8 v;
    if (kStep < 64) {
        int kk = kStep * 32 + quad * 8;
        if (kk < IN_SZ) {
            const float4 u0 = *(const float4*)&u[(size_t)o * IN_SZ + kk];
            const float4 u1 = *(const float4*)&u[(size_t)o * IN_SZ + kk + 4];
            float uf[8] = {u0.x, u0.y, u0.z, u0.w, u1.x, u1.y, u1.z, u1.w};
            #pragma unroll
            for (int j = 0; j < 8; ++j) v[j] = (__bf16)(uf[j] * uf[j]);
        } else {
            int i0 = kk - IN_SZ;
            const float4 u0 = *(const float4*)&u[(size_t)o * IN_SZ + i0];
            const float4 u1 = *(const float4*)&u[(size_t)o * IN_SZ + i0 + 4];
            const float4 w0 = *(const float4*)&w[(size_t)o * IN_SZ + i0];
            const float4 w1 = *(const float4*)&w[(size_t)o * IN_SZ + i0 + 4];
            float uf[8] = {u0.x, u0.y, u0.z, u0.w, u1.x, u1.y, u1.z, u1.w};
            float wf[8] = {w0.x, w0.y, w0.z, w0.w, w1.x, w1.y, w1.z, w1.w};
            #pragma unroll
            for (int j = 0; j < 8; ++j) v[j] = (__bf16)(-2.f * uf[j] * uf[j] * wf[j]);
        }
    } else {
        #pragma unroll
        for (int j = 0; j < 8; ++j) v[j] = (__bf16)0.f;
    }
    *(bf16x8*)&Bsh[(size_t)t * 8] = v;
}

// r[o] = sum_i (u*w)^2  -> B_shuf[o>>4][64][lane = o&15 (quad 0)][j=0]
__global__ __launch_bounds__(256) void rbf_prep_r(
    const float* __restrict__ w, const float* __restrict__ u,
    __bf16* __restrict__ Bsh)
{
    int wave = threadIdx.x >> 6;
    int lane = threadIdx.x & 63;
    int o    = blockIdx.x * 4 + wave;                // 128 blocks x 4 waves

    float s = 0.f;
    #pragma unroll
    for (int c = 0; c < 4; ++c) {
        int i = lane * 16 + c * 4;
        const float4 uv = *(const float4*)&u[(size_t)o * IN_SZ + i];
        const float4 wv = *(const float4*)&w[(size_t)o * IN_SZ + i];
        float t0 = uv.x * wv.x, t1 = uv.y * wv.y, t2 = uv.z * wv.z, t3 = uv.w * wv.w;
        s += t0 * t0 + t1 * t1 + t2 * t2 + t3 * t3;
    }
    #pragma unroll
    for (int d = 32; d > 0; d >>= 1) s += __shfl_down(s, d);
    if (lane == 0) {
        size_t idx = (((size_t)(o >> 4) * NKSTEP + 64) * 64 + (o & 15)) * 8;
        Bsh[idx] = (__bf16)s;
    }
}

// GEMM: C[b][o] = sum_k A.B  (includes bias via k-step 64). Split-K=2.
// Block = 64x64 output tile, 4 waves each a 32x32 quadrant (2x2 frags of 16x16x32).
__global__ __launch_bounds__(256) void rbf_gemm(
    const __bf16* __restrict__ Ash, const __bf16* __restrict__ Bsh,
    float* __restrict__ part)
{
    const int t    = threadIdx.x;
    const int lane = t & 63;
    const int wv   = t >> 6;
    const int mt2  = wv >> 1;                        // 0..1
    const int nt2  = wv & 1;                         // 0..1
    const int kz   = blockIdx.z;

    const int mTile0 = blockIdx.x * 4 + mt2 * 2;     // two m-tiles: +0, +1
    const int nTile0 = blockIdx.y * 4 + nt2 * 2;     // two n-tiles: +0, +1

    const int kLo = kz ? 33 : 0;
    const int kHi = kz ? NKSTEP : 33;

    f32x4 acc[2][2] = {};

    const __bf16* pa0 = &Ash[(((size_t)mTile0       * NKSTEP + kLo) * 64 + lane) * 8];
    const __bf16* pa1 = &Ash[(((size_t)(mTile0 + 1) * NKSTEP + kLo) * 64 + lane) * 8];
    const __bf16* pb0 = &Bsh[(((size_t)nTile0       * NKSTEP + kLo) * 64 + lane) * 8];
    const __bf16* pb1 = &Bsh[(((size_t)(nTile0 + 1) * NKSTEP + kLo) * 64 + lane) * 8];

    #pragma unroll 4
    for (int ks = kLo; ks < kHi; ++ks) {
        bf16x8 a0 = *(const bf16x8*)pa0;  pa0 += 64 * 8;   // coalesced 1KB/wave loads
        bf16x8 a1 = *(const bf16x8*)pa1;  pa1 += 64 * 8;
        bf16x8 b0 = *(const bf16x8*)pb0;  pb0 += 64 * 8;
        bf16x8 b1 = *(const bf16x8*)pb1;  pb1 += 64 * 8;
        acc[0][0] = __builtin_amdgcn_mfma_f32_16x16x32_bf16(a0, b0, acc[0][0], 0, 0, 0);
        acc[0][1] = __builtin_amdgcn_mfma_f32_16x16x32_bf16(a0, b1, acc[0][1], 0, 0, 0);
        acc[1][0] = __builtin_amdgcn_mfma_f32_16x16x32_bf16(a1, b0, acc[1][0], 0, 0, 0);
        acc[1][1] = __builtin_amdgcn_mfma_f32_16x16x32_bf16(a1, b1, acc[1][1], 0, 0, 0);
    }

    // C/D layout: col = lane&15 (o), row = (lane>>4)*4 + reg (b)   [m89-verified]
    const int quad = lane >> 4;
    #pragma unroll
    for (int mi = 0; mi < 2; ++mi) {
        int b = (mTile0 + mi) * 16 + quad * 4;
        #pragma unroll
        for (int ni = 0; ni < 2; ++ni) {
            int o = (nTile0 + ni) * 16 + (lane & 15);
            #pragma unroll
            for (int r = 0; r < 4; ++r)
                part[((size_t)kz * B_SZ + (b + r)) * OUT_SZ + o] = acc[mi][ni][r];
        }
    }
}

// out = a + exp(-z)*(1-2a),  z = part0 + part1
__global__ __launch_bounds__(256) void rbf_reduce(
    const float* __restrict__ part, const float* __restrict__ andor,
    float* __restrict__ out)
{
    int idx = blockIdx.x * 256 + threadIdx.x;
    if (idx < B_SZ * OUT_SZ) {
        float z = part[idx] + part[(size_t)B_SZ * OUT_SZ + idx];
        float a = andor[idx & (OUT_SZ - 1)];
        float y = __expf(-z);
        out[idx] = fmaf(y, 1.f - 2.f * a, a);
    }
}

extern "C" void kernel_launch(void* const* d_in, const int* in_sizes, int n_in,
                              void* d_out, int out_size, void* d_ws, size_t ws_size,
                              hipStream_t stream) {
    const float* x = (const float*)d_in[0];   // [B, IN]
    const float* w = (const float*)d_in[1];   // [OUT, IN]
    const float* u = (const float*)d_in[2];   // [OUT, IN]
    const float* a = (const float*)d_in[3];   // [1, OUT]
    float* out = (float*)d_out;               // [B, OUT]

    char* ws = (char*)d_ws;
    __bf16* Ash = (__bf16*)ws;
    __bf16* Bsh = (__bf16*)(ws + OFF_B);
    float*  prt = (float*)(ws + OFF_P);

    rbf_prep_a<<<dim3((MT * NKSTEP * 64) / 256), dim3(256), 0, stream>>>(x, Ash);
    rbf_prep_b<<<dim3((NT * NKSTEP * 64) / 256), dim3(256), 0, stream>>>(w, u, Bsh);
    rbf_prep_r<<<dim3(OUT_SZ / 4), dim3(256), 0, stream>>>(w, u, Bsh);

    rbf_gemm<<<dim3(B_SZ / 64, OUT_SZ / 64, 2), dim3(256), 0, stream>>>(Ash, Bsh, prt);

    rbf_reduce<<<dim3((B_SZ * OUT_SZ) / 256), dim3(256), 0, stream>>>(prt, a, out);
}

// Round 5
// 86.573 us; speedup vs baseline: 5.5059x; 1.0050x over previous
//
#include <hip/hip_runtime.h>

#define B_SZ   1024
#define OUT_SZ 512
#define IN_SZ  1024
#define NKSTEP 65                // 64 real k-steps of 32 + 1 bias step
#define MT     64                // M tiles of 16
#define NT     32                // N tiles of 16

typedef __bf16 bf16x8 __attribute__((ext_vector_type(8)));
typedef float  f32x4  __attribute__((ext_vector_type(4)));

// ---- workspace layout (16B aligned) ----
// A_shuf: [MT][NKSTEP][64 lanes][8] bf16 = 4,259,840 B
// B_shuf: [NT][NKSTEP][64 lanes][8] bf16 = 2,129,920 B
#define A_ELEMS ((size_t)MT * NKSTEP * 64 * 8)
#define B_ELEMS ((size_t)NT * NKSTEP * 64 * 8)
#define OFF_B   (A_ELEMS * 2)

#define NBLK_A  (MT * NKSTEP / 4)        // 1040 blocks (256 thr = 4 (tile,kstep) rows)
#define NBLK_B  (NT * NKSTEP / 4)        // 520
#define NBLK_R  (OUT_SZ / 4)             // 128

// Fused prep: blocks [0,NBLK_A) shuffle A, [NBLK_A, NBLK_A+NBLK_B) shuffle B,
// rest compute r[o]=sum (u*w)^2 into B's bias k-step.
// Race-safety (same dispatch, undefined block order): at kStep==64 the B path
// skips quad==0 lanes entirely; the r path writes those 16B slots whole.
__global__ __launch_bounds__(256) void rbf_prep(
    const float* __restrict__ x, const float* __restrict__ w,
    const float* __restrict__ u, __bf16* __restrict__ Ash,
    __bf16* __restrict__ Bsh)
{
    const int blk = blockIdx.x;

    if (blk < NBLK_A) {
        // A_shuf[mTile][kStep][lane][j] = A[b=mTile*16+(lane&15)][k=kStep*32+(lane>>4)*8+j]
        // A[b][k] = x^2 (k<1024) | x (k<2048) | bias col: 1 at (quad0,j0)
        int t = blk * 256 + threadIdx.x;
        int lane  = t & 63;
        int tmp   = t >> 6;
        int kStep = tmp % NKSTEP;
        int mTile = tmp / NKSTEP;
        int b     = mTile * 16 + (lane & 15);
        int quad  = lane >> 4;

        bf16x8 v;
        if (kStep < 64) {
            int kk = kStep * 32 + quad * 8;
            if (kk < IN_SZ) {
                const float4 f0 = *(const float4*)&x[(size_t)b * IN_SZ + kk];
                const float4 f1 = *(const float4*)&x[(size_t)b * IN_SZ + kk + 4];
                float f[8] = {f0.x, f0.y, f0.z, f0.w, f1.x, f1.y, f1.z, f1.w};
                #pragma unroll
                for (int j = 0; j < 8; ++j) v[j] = (__bf16)(f[j] * f[j]);
            } else {
                int i0 = kk - IN_SZ;
                const float4 f0 = *(const float4*)&x[(size_t)b * IN_SZ + i0];
                const float4 f1 = *(const float4*)&x[(size_t)b * IN_SZ + i0 + 4];
                float f[8] = {f0.x, f0.y, f0.z, f0.w, f1.x, f1.y, f1.z, f1.w};
                #pragma unroll
                for (int j = 0; j < 8; ++j) v[j] = (__bf16)f[j];
            }
        } else {
            #pragma unroll
            for (int j = 0; j < 8; ++j) v[j] = (__bf16)0.f;
            if (quad == 0) v[0] = (__bf16)1.f;
        }
        *(bf16x8*)&Ash[(size_t)t * 8] = v;
    } else if (blk < NBLK_A + NBLK_B) {
        // B_shuf[nTile][kStep][lane][j]: u^2 (k<1024) | -2u^2w (k<2048) | bias step
        int t = (blk - NBLK_A) * 256 + threadIdx.x;
        int lane  = t & 63;
        int tmp   = t >> 6;
        int kStep = tmp % NKSTEP;
        int nTile = tmp / NKSTEP;
        int o     = nTile * 16 + (lane & 15);
        int quad  = lane >> 4;

        bf16x8 v;
        if (kStep < 64) {
            int kk = kStep * 32 + quad * 8;
            if (kk < IN_SZ) {
                const float4 u0 = *(const float4*)&u[(size_t)o * IN_SZ + kk];
                const float4 u1 = *(const float4*)&u[(size_t)o * IN_SZ + kk + 4];
                float uf[8] = {u0.x, u0.y, u0.z, u0.w, u1.x, u1.y, u1.z, u1.w};
                #pragma unroll
                for (int j = 0; j < 8; ++j) v[j] = (__bf16)(uf[j] * uf[j]);
            } else {
                int i0 = kk - IN_SZ;
                const float4 u0 = *(const float4*)&u[(size_t)o * IN_SZ + i0];
                const float4 u1 = *(const float4*)&u[(size_t)o * IN_SZ + i0 + 4];
                const float4 w0 = *(const float4*)&w[(size_t)o * IN_SZ + i0];
                const float4 w1 = *(const float4*)&w[(size_t)o * IN_SZ + i0 + 4];
                float uf[8] = {u0.x, u0.y, u0.z, u0.w, u1.x, u1.y, u1.z, u1.w};
                float wf[8] = {w0.x, w0.y, w0.z, w0.w, w1.x, w1.y, w1.z, w1.w};
                #pragma unroll
                for (int j = 0; j < 8; ++j) v[j] = (__bf16)(-2.f * uf[j] * uf[j] * wf[j]);
            }
            *(bf16x8*)&Bsh[(size_t)t * 8] = v;
        } else if (quad != 0) {
            // bias step, non-bias lanes: A is 0 there, but keep it clean zero.
            #pragma unroll
            for (int j = 0; j < 8; ++j) v[j] = (__bf16)0.f;
            *(bf16x8*)&Bsh[(size_t)t * 8] = v;
        }
        // quad==0 at kStep==64: written by the r path below (whole 16B slot).
    } else {
        // r[o] = sum_i (u*w)^2 -> B_shuf[o>>4][64][o&15][0], rest of 16B zero
        int wave = threadIdx.x >> 6;
        int lane = threadIdx.x & 63;
        int o    = (blk - NBLK_A - NBLK_B) * 4 + wave;

        float s = 0.f;
        #pragma unroll
        for (int c = 0; c < 4; ++c) {
            int i = lane * 16 + c * 4;
            const float4 uv = *(const float4*)&u[(size_t)o * IN_SZ + i];
            const float4 wv = *(const float4*)&w[(size_t)o * IN_SZ + i];
            float t0 = uv.x * wv.x, t1 = uv.y * wv.y, t2 = uv.z * wv.z, t3 = uv.w * wv.w;
            s += t0 * t0 + t1 * t1 + t2 * t2 + t3 * t3;
        }
        #pragma unroll
        for (int d = 32; d > 0; d >>= 1) s += __shfl_down(s, d);
        if (lane == 0) {
            bf16x8 vr;
            #pragma unroll
            for (int j = 0; j < 8; ++j) vr[j] = (__bf16)0.f;
            vr[0] = (__bf16)s;
            size_t idx = ((size_t)(o >> 4) * NKSTEP + 64) * 64 + (o & 15);
            *(bf16x8*)&Bsh[idx * 8] = vr;
        }
    }
}

// GEMM over full K (65 steps incl. bias) + fused exp/mix epilogue -> d_out.
// Block = 64x64 output tile, 4 waves each a 32x32 quadrant (2x2 frags 16x16x32).
__global__ __launch_bounds__(256) void rbf_gemm(
    const __bf16* __restrict__ Ash, const __bf16* __restrict__ Bsh,
    const float* __restrict__ andor, float* __restrict__ out)
{
    const int t    = threadIdx.x;
    const int lane = t & 63;
    const int wv   = t >> 6;
    const int mt2  = wv >> 1;
    const int nt2  = wv & 1;

    const int mTile0 = blockIdx.x * 4 + mt2 * 2;
    const int nTile0 = blockIdx.y * 4 + nt2 * 2;

    f32x4 acc[2][2] = {};

    const __bf16* pa0 = &Ash[(((size_t)mTile0       * NKSTEP) * 64 + lane) * 8];
    const __bf16* pa1 = &Ash[(((size_t)(mTile0 + 1) * NKSTEP) * 64 + lane) * 8];
    const __bf16* pb0 = &Bsh[(((size_t)nTile0       * NKSTEP) * 64 + lane) * 8];
    const __bf16* pb1 = &Bsh[(((size_t)(nTile0 + 1) * NKSTEP) * 64 + lane) * 8];

    #pragma unroll 5
    for (int ks = 0; ks < NKSTEP; ++ks) {
        bf16x8 a0 = *(const bf16x8*)pa0;  pa0 += 64 * 8;   // coalesced 1KB/wave
        bf16x8 a1 = *(const bf16x8*)pa1;  pa1 += 64 * 8;
        bf16x8 b0 = *(const bf16x8*)pb0;  pb0 += 64 * 8;
        bf16x8 b1 = *(const bf16x8*)pb1;  pb1 += 64 * 8;
        acc[0][0] = __builtin_amdgcn_mfma_f32_16x16x32_bf16(a0, b0, acc[0][0], 0, 0, 0);
        acc[0][1] = __builtin_amdgcn_mfma_f32_16x16x32_bf16(a0, b1, acc[0][1], 0, 0, 0);
        acc[1][0] = __builtin_amdgcn_mfma_f32_16x16x32_bf16(a1, b0, acc[1][0], 0, 0, 0);
        acc[1][1] = __builtin_amdgcn_mfma_f32_16x16x32_bf16(a1, b1, acc[1][1], 0, 0, 0);
    }

    // C/D: col = lane&15 (o), row = (lane>>4)*4 + reg (b)   [m89-verified]
    const int quad = lane >> 4;
    #pragma unroll
    for (int ni = 0; ni < 2; ++ni) {
        int o = (nTile0 + ni) * 16 + (lane & 15);
        float a  = andor[o];
        float s1 = 1.f - 2.f * a;
        #pragma unroll
        for (int mi = 0; mi < 2; ++mi) {
            int b = (mTile0 + mi) * 16 + quad * 4;
            #pragma unroll
            for (int r = 0; r < 4; ++r) {
                float y = __expf(-acc[mi][ni][r]);
                out[(size_t)(b + r) * OUT_SZ + o] = fmaf(y, s1, a);
            }
        }
    }
}

extern "C" void kernel_launch(void* const* d_in, const int* in_sizes, int n_in,
                              void* d_out, int out_size, void* d_ws, size_t ws_size,
                              hipStream_t stream) {
    const float* x = (const float*)d_in[0];   // [B, IN]
    const float* w = (const float*)d_in[1];   // [OUT, IN]
    const float* u = (const float*)d_in[2];   // [OUT, IN]
    const float* a = (const float*)d_in[3];   // [1, OUT]
    float* out = (float*)d_out;               // [B, OUT]

    char* ws = (char*)d_ws;
    __bf16* Ash = (__bf16*)ws;
    __bf16* Bsh = (__bf16*)(ws + OFF_B);

    rbf_prep<<<dim3(NBLK_A + NBLK_B + NBLK_R), dim3(256), 0, stream>>>(x, w, u, Ash, Bsh);
    rbf_gemm<<<dim3(B_SZ / 64, OUT_SZ / 64), dim3(256), 0, stream>>>(Ash, Bsh, a, out);
}

// Round 6
// 74.851 us; speedup vs baseline: 6.3682x; 1.1566x over previous
//
#include <hip/hip_runtime.h>

#define B_SZ   1024
#define OUT_SZ 512
#define IN_SZ  1024

#define MB 64                 // b-rows per block
#define NB 64                 // o-rows per block
#define KSPLIT 4
#define KSL (IN_SZ / KSPLIT)  // 256 raw k per block
#define CH  64                // raw k per chunk
#define NCH (KSL / CH)        // 4 chunks

typedef __bf16 bf16x8 __attribute__((ext_vector_type(8)));
typedef __bf16 bf16x4 __attribute__((ext_vector_type(4)));
typedef float  f32x4  __attribute__((ext_vector_type(4)));

// LDS fragment-native bf16 tiles. Layout: [seg][s][frag16][slot][j]
//   seg: A: 0=x^2, 1=x   B: 0=u^2, 1=-2u^2w, 2=(uw)^2
//   s: which 32-k MFMA step inside the 64-k chunk
//   slot: XOR-swizzled lane slot = quad*16 + ((row16 ^ quad) & 15)
#define A_IDX(seg, s, mf, slot) (((((seg)*2 + (s))*4 + (mf))*64 + (slot))*8)
#define B_IDX(seg, s, nf, slot) (((((seg)*2 + (s))*4 + (nf))*64 + (slot))*8)

// One fused kernel: raw x,u,w -> bf16 frags in LDS -> MFMA -> fp32 partials.
// No ws intermediates to round-trip; r-bias via ones-fragment into acc_r.
__global__ __launch_bounds__(256) void rbf_fused(
    const float* __restrict__ x, const float* __restrict__ w,
    const float* __restrict__ u, float* __restrict__ part)
{
    __shared__ __bf16 Asm[2 * 2 * 4 * 64 * 8];   // 16 KB
    __shared__ __bf16 Bsm[3 * 2 * 4 * 64 * 8];   // 24 KB

    const int t     = threadIdx.x;
    const int lane  = t & 63;
    const int wv    = t >> 6;
    const int wm    = wv >> 1;                   // wave quadrant in m
    const int wn    = wv & 1;                    // wave quadrant in n
    const int mBase = blockIdx.x * MB;
    const int nBase = blockIdx.y * NB;
    const int kz    = blockIdx.z;
    const int kBase = kz * KSL;

    f32x4 acc[2][2] = {};
    f32x4 acc_r[2]  = {};

    bf16x8 ones;
    #pragma unroll
    for (int j = 0; j < 8; ++j) ones[j] = (__bf16)1.f;

    float4 xr[4], ur[4], wr[4];

    // coalesced loads: per i, lanes sweep 16 float4 (256B) per row, 4 rows/wave
    auto load_regs = [&](int c) {
        #pragma unroll
        for (int i = 0; i < 4; ++i) {
            int id  = i * 256 + t;
            int row = id >> 4;
            int gk  = kBase + c * CH + (id & 15) * 4;
            xr[i] = *(const float4*)&x[(size_t)(mBase + row) * IN_SZ + gk];
            ur[i] = *(const float4*)&u[(size_t)(nBase + row) * IN_SZ + gk];
            wr[i] = *(const float4*)&w[(size_t)(nBase + row) * IN_SZ + gk];
        }
    };

    auto write_lds = [&]() {
        #pragma unroll
        for (int i = 0; i < 4; ++i) {
            int id    = i * 256 + t;
            int row   = id >> 4;
            int row16 = row & 15;
            int frag  = row >> 4;
            int kl    = (id & 15) * 4;
            int s     = kl >> 5;
            int quad  = (kl >> 3) & 3;
            int j0    = kl & 7;                  // 0 or 4
            int slot  = quad * 16 + ((row16 ^ quad) & 15);

            float xv[4] = {xr[i].x, xr[i].y, xr[i].z, xr[i].w};
            float uv[4] = {ur[i].x, ur[i].y, ur[i].z, ur[i].w};
            float wv4[4] = {wr[i].x, wr[i].y, wr[i].z, wr[i].w};
            bf16x4 a0, a1, b0, b1, b2;
            #pragma unroll
            for (int e = 0; e < 4; ++e) {
                float xe = xv[e], ue = uv[e], we = wv4[e];
                float u2 = ue * ue;
                float uw = ue * we;
                a0[e] = (__bf16)(xe * xe);
                a1[e] = (__bf16)xe;
                b0[e] = (__bf16)u2;
                b1[e] = (__bf16)(-2.f * u2 * we);
                b2[e] = (__bf16)(uw * uw);
            }
            *(bf16x4*)&Asm[A_IDX(0, s, frag, slot) + j0] = a0;
            *(bf16x4*)&Asm[A_IDX(1, s, frag, slot) + j0] = a1;
            *(bf16x4*)&Bsm[B_IDX(0, s, frag, slot) + j0] = b0;
            *(bf16x4*)&Bsm[B_IDX(1, s, frag, slot) + j0] = b1;
            *(bf16x4*)&Bsm[B_IDX(2, s, frag, slot) + j0] = b2;
        }
    };

    // read slot for this lane (same swizzle); reads are a permutation of
    // aligned 16B slots -> conflict-free b128 like the m97 pattern.
    const int r_quad = lane >> 4;
    const int r_slot = r_quad * 16 + (((lane & 15) ^ r_quad) & 15);
    const int mf0 = wm * 2, nf0 = wn * 2;

    load_regs(0);

    for (int c = 0; c < NCH; ++c) {
        __syncthreads();                         // prev compute done with LDS
        write_lds();
        __syncthreads();
        if (c + 1 < NCH) load_regs(c + 1);       // prefetch behind MFMAs

        #pragma unroll
        for (int seg = 0; seg < 2; ++seg)
            #pragma unroll
            for (int s = 0; s < 2; ++s) {
                bf16x8 am0 = *(const bf16x8*)&Asm[A_IDX(seg, s, mf0,     r_slot)];
                bf16x8 am1 = *(const bf16x8*)&Asm[A_IDX(seg, s, mf0 + 1, r_slot)];
                bf16x8 bn0 = *(const bf16x8*)&Bsm[B_IDX(seg, s, nf0,     r_slot)];
                bf16x8 bn1 = *(const bf16x8*)&Bsm[B_IDX(seg, s, nf0 + 1, r_slot)];
                acc[0][0] = __builtin_amdgcn_mfma_f32_16x16x32_bf16(am0, bn0, acc[0][0], 0, 0, 0);
                acc[0][1] = __builtin_amdgcn_mfma_f32_16x16x32_bf16(am0, bn1, acc[0][1], 0, 0, 0);
                acc[1][0] = __builtin_amdgcn_mfma_f32_16x16x32_bf16(am1, bn0, acc[1][0], 0, 0, 0);
                acc[1][1] = __builtin_amdgcn_mfma_f32_16x16x32_bf16(am1, bn1, acc[1][1], 0, 0, 0);
            }
        #pragma unroll
        for (int s = 0; s < 2; ++s) {
            bf16x8 b20 = *(const bf16x8*)&Bsm[B_IDX(2, s, nf0,     r_slot)];
            bf16x8 b21 = *(const bf16x8*)&Bsm[B_IDX(2, s, nf0 + 1, r_slot)];
            acc_r[0] = __builtin_amdgcn_mfma_f32_16x16x32_bf16(ones, b20, acc_r[0], 0, 0, 0);
            acc_r[1] = __builtin_amdgcn_mfma_f32_16x16x32_bf16(ones, b21, acc_r[1], 0, 0, 0);
        }
    }

    // C/D: col = lane&15 (o), row = quad*4 + reg (b). acc_r rows all equal r[o].
    const int col = lane & 15;
    #pragma unroll
    for (int mi = 0; mi < 2; ++mi) {
        int b = mBase + (wm * 2 + mi) * 16 + r_quad * 4;
        #pragma unroll
        for (int ni = 0; ni < 2; ++ni) {
            int o = nBase + (wn * 2 + ni) * 16 + col;
            #pragma unroll
            for (int r = 0; r < 4; ++r)
                part[((size_t)kz * B_SZ + (b + r)) * OUT_SZ + o] =
                    acc[mi][ni][r] + acc_r[ni][r];
        }
    }
}

// z = sum_kz part, out = a + exp(-z)*(1-2a)
__global__ __launch_bounds__(256) void rbf_reduce(
    const float* __restrict__ part, const float* __restrict__ andor,
    float* __restrict__ out)
{
    int idx = blockIdx.x * 256 + threadIdx.x;
    if (idx < B_SZ * OUT_SZ) {
        float z = 0.f;
        #pragma unroll
        for (int kz = 0; kz < KSPLIT; ++kz)
            z += part[(size_t)kz * (B_SZ * OUT_SZ) + idx];
        float a = andor[idx & (OUT_SZ - 1)];
        float y = __expf(-z);
        out[idx] = fmaf(y, 1.f - 2.f * a, a);
    }
}

extern "C" void kernel_launch(void* const* d_in, const int* in_sizes, int n_in,
                              void* d_out, int out_size, void* d_ws, size_t ws_size,
                              hipStream_t stream) {
    const float* x = (const float*)d_in[0];   // [B, IN]
    const float* w = (const float*)d_in[1];   // [OUT, IN]
    const float* u = (const float*)d_in[2];   // [OUT, IN]
    const float* a = (const float*)d_in[3];   // [1, OUT]
    float* out = (float*)d_out;               // [B, OUT]

    float* part = (float*)d_ws;               // [KSPLIT][B][OUT] = 8 MB

    dim3 grid(B_SZ / MB, OUT_SZ / NB, KSPLIT);   // 16 x 8 x 4 = 512 blocks
    rbf_fused<<<grid, dim3(256), 0, stream>>>(x, w, u, part);
    rbf_reduce<<<dim3((B_SZ * OUT_SZ) / 256), dim3(256), 0, stream>>>(part, a, out);
}